// Round 1
// baseline (510.856 us; speedup 1.0000x reference)
//
#include <hip/hip_runtime.h>

typedef _Float16 f16;
typedef _Float16 f16x8 __attribute__((ext_vector_type(8)));
typedef float f32x4 __attribute__((ext_vector_type(4)));

static __device__ __forceinline__ f32x4 mfma16(f16x8 a, f16x8 b, f32x4 c) {
  return __builtin_amdgcn_mfma_f32_16x16x32_f16(a, b, c, 0, 0, 0);
}

// ---------------- pack kernels ----------------
__global__ void pack_f16_kernel(const float* __restrict__ s, f16* __restrict__ d, int n) {
  int i = blockIdx.x * 256 + threadIdx.x;
  if (i < n) d[i] = (f16)s[i];
}

// relVT[d][p] = relative_v[p][d], padded col p==2047 -> 0
__global__ void pack_relvt_kernel(const float* __restrict__ relv, f16* __restrict__ dst) {
  int idx = blockIdx.x * 256 + threadIdx.x;  // 64*2048 threads
  int dd = idx >> 11, p = idx & 2047;
  dst[idx] = (p < 2047) ? (f16)relv[p * 64 + dd] : (f16)0.f;
}

// ---------------- generic B^T GEMM: C[i,j] = (sum_k A[i,k]*B[j,k] + bias)*oscale ----
template <int OUT_F32, int BIAS_ROW>
__global__ __launch_bounds__(256, 2) void gemm_bt(
    const f16* __restrict__ A, const f16* __restrict__ B,
    const float* __restrict__ bias, void* __restrict__ Cout,
    int M, int N, int Kd, float oscale) {
  __shared__ __align__(16) f16 Al[128 * 72];
  __shared__ __align__(16) f16 Bl[128 * 72];
  const int tid = threadIdx.x;
  const int w = tid >> 6, lane = tid & 63;
  const int l15 = lane & 15, hi = lane >> 4;
  const long i0 = (long)blockIdx.y * 128, j0 = (long)blockIdx.x * 128;
  const int wr = (w >> 1) * 64, wc = (w & 1) * 64;

  f32x4 acc[4][4];
#pragma unroll
  for (int a = 0; a < 4; a++)
#pragma unroll
    for (int b2 = 0; b2 < 4; b2++) acc[a][b2] = (f32x4){0.f, 0.f, 0.f, 0.f};

  for (int k0 = 0; k0 < Kd; k0 += 64) {
    __syncthreads();
#pragma unroll
    for (int s = 0; s < 4; s++) {
      int tau = tid + 256 * s;
      int r = tau >> 3, c = (tau & 7) * 8;
      *(uint4*)&Al[r * 72 + c] = *(const uint4*)(A + (i0 + r) * Kd + k0 + c);
      *(uint4*)&Bl[r * 72 + c] = *(const uint4*)(B + (j0 + r) * Kd + k0 + c);
    }
    __syncthreads();
#pragma unroll
    for (int ks = 0; ks < 2; ks++) {
      f16x8 af[4], bf[4];
#pragma unroll
      for (int mb = 0; mb < 4; mb++)
        af[mb] = *(const f16x8*)&Al[(wr + mb * 16 + l15) * 72 + ks * 32 + hi * 8];
#pragma unroll
      for (int nb = 0; nb < 4; nb++)
        bf[nb] = *(const f16x8*)&Bl[(wc + nb * 16 + l15) * 72 + ks * 32 + hi * 8];
#pragma unroll
      for (int mb = 0; mb < 4; mb++)
#pragma unroll
        for (int nb = 0; nb < 4; nb++) acc[mb][nb] = mfma16(af[mb], bf[nb], acc[mb][nb]);
    }
  }
#pragma unroll
  for (int mb = 0; mb < 4; mb++) {
#pragma unroll
    for (int nb = 0; nb < 4; nb++) {
      long row = i0 + wr + mb * 16 + hi * 4;
      long col = j0 + wc + nb * 16 + l15;
      float bc = BIAS_ROW ? 0.f : bias[col];
#pragma unroll
      for (int i = 0; i < 4; i++) {
        float v = acc[mb][nb][i] + (BIAS_ROW ? bias[row + i] : bc);
        v *= oscale;
        if (OUT_F32)
          ((float*)Cout)[(row + i) * N + col] = v;
        else
          ((f16*)Cout)[(row + i) * N + col] = (f16)v;
      }
    }
  }
}

// ---------------- fused relative-position flash attention ----------------
// grid: (16 qtiles, 128 b*h). 4 waves, BM=BN=64.
// Qh,Kh row-major [8192][1024] (K pre-scaled by 1/8); Vth [1024][8192] (V^T);
// relKh [2047][64]; relVTh [64][2048] (relV^T, col 2047 zero); AO [8192][1024] f16.
__global__ __launch_bounds__(256, 2) void attn_kernel(
    const f16* __restrict__ Qh, const f16* __restrict__ Kh,
    const f16* __restrict__ Vth, const f16* __restrict__ relKh,
    const f16* __restrict__ relVTh, f16* __restrict__ AO) {
  __shared__ __align__(16) f16 buf1[64 * 72];   // K tile / Vt tile
  __shared__ __align__(16) f16 buf2[128 * 72];  // relK band [128][72] / Pskew [64][136]
  __shared__ __align__(16) f16 buf3[64 * 136];  // QR [64][136] / relVT band [64][136]
  __shared__ __align__(16) f16 buf4[64 * 72];   // Pmain [64][72]

  const int tid = threadIdx.x;
  const int w = tid >> 6, lane = tid & 63;
  const int l15 = lane & 15, hi = lane >> 4;
  const int qt = blockIdx.x, bh = blockIdx.y;
  const int b = bh >> 4, h = bh & 15;
  const int l0 = qt * 64;

  // Q fragments (row = l0 + 16w + l15), k-halves ks=0,1
  const long qoff = ((long)(b * 1024 + l0 + w * 16 + l15)) * 1024 + h * 64 + hi * 8;
  const f16x8 qf0 = *(const f16x8*)(Qh + qoff);
  const f16x8 qf1 = *(const f16x8*)(Qh + qoff + 32);

  f32x4 acc_o[4];
#pragma unroll
  for (int cf = 0; cf < 4; cf++) acc_o[cf] = (f32x4){0.f, 0.f, 0.f, 0.f};
  float mrow[4] = {-1e30f, -1e30f, -1e30f, -1e30f};
  float lsum[4] = {0.f, 0.f, 0.f, 0.f};

  for (int kt = 0; kt < 16; kt++) {
    const int r0 = kt * 64;
    const int base = 960 + r0 - l0;  // relK/relV band start (multiple of 64, >=0)
    __syncthreads();  // B0: prev iter's MFMA reads done before overwrite

    // preload V^T tile + relVT band into registers (hide global latency)
    uint4 vreg[2], rvreg[4];
#pragma unroll
    for (int s = 0; s < 2; s++) {
      int tau = tid + 256 * s;
      int d = tau >> 3, c = (tau & 7) * 8;
      vreg[s] = *(const uint4*)(Vth + ((long)(h * 64 + d)) * 8192 + b * 1024 + r0 + c);
    }
#pragma unroll
    for (int s = 0; s < 4; s++) {
      int tau = tid + 256 * s;
      int d = tau >> 4, c = (tau & 15) * 8;
      rvreg[s] = *(const uint4*)(relVTh + d * 2048 + base + c);
    }
    // stage K tile -> buf1, relK band -> buf2
#pragma unroll
    for (int s = 0; s < 2; s++) {
      int tau = tid + 256 * s;
      int r = tau >> 3, c = (tau & 7) * 8;
      *(uint4*)&buf1[r * 72 + c] =
          *(const uint4*)(Kh + ((long)(b * 1024 + r0 + r)) * 1024 + h * 64 + c);
    }
#pragma unroll
    for (int s = 0; s < 4; s++) {
      int tau = tid + 256 * s;
      int r = tau >> 3, c = (tau & 7) * 8;
      *(uint4*)&buf2[r * 72 + c] = *(const uint4*)(relKh + (base + r) * 64 + c);
    }
    __syncthreads();  // B1

    // S = Q*(K/8)^T ; QR[l,c] = Q[l,:].relK[base+c,:]
    f32x4 sacc[4], qracc[8];
#pragma unroll
    for (int cf = 0; cf < 4; cf++) sacc[cf] = (f32x4){0.f, 0.f, 0.f, 0.f};
#pragma unroll
    for (int cf = 0; cf < 8; cf++) qracc[cf] = (f32x4){0.f, 0.f, 0.f, 0.f};
#pragma unroll
    for (int ks = 0; ks < 2; ks++) {
      f16x8 qf = ks ? qf1 : qf0;
#pragma unroll
      for (int cf = 0; cf < 4; cf++) {
        f16x8 kf = *(const f16x8*)&buf1[(cf * 16 + l15) * 72 + ks * 32 + hi * 8];
        sacc[cf] = mfma16(qf, kf, sacc[cf]);
      }
#pragma unroll
      for (int cf = 0; cf < 8; cf++) {
        f16x8 rf = *(const f16x8*)&buf2[(cf * 16 + l15) * 72 + ks * 32 + hi * 8];
        qracc[cf] = mfma16(qf, rf, qracc[cf]);
      }
    }
    // write QR to buf3 (fp16)
#pragma unroll
    for (int cf = 0; cf < 8; cf++)
#pragma unroll
      for (int i = 0; i < 4; i++)
        buf3[(w * 16 + hi * 4 + i) * 136 + cf * 16 + l15] = (f16)qracc[cf][i];
    __syncthreads();  // B2: QR visible; K reads done -> buf1 reusable

    // stage V^T tile from regs (overlaps softmax)
#pragma unroll
    for (int s = 0; s < 2; s++) {
      int tau = tid + 256 * s;
      int d = tau >> 3, c = (tau & 7) * 8;
      *(uint4*)&buf1[d * 72 + c] = vreg[s];
    }
    // gather rel scores + online softmax
    float sv[4][4];
#pragma unroll
    for (int cf = 0; cf < 4; cf++)
#pragma unroll
      for (int i = 0; i < 4; i++) {
        int li = w * 16 + hi * 4 + i;
        int ri = cf * 16 + l15;
        sv[cf][i] = sacc[cf][i] + (float)buf3[li * 136 + 63 + ri - li];
      }
    float rmax[4];
#pragma unroll
    for (int i = 0; i < 4; i++)
      rmax[i] = fmaxf(fmaxf(sv[0][i], sv[1][i]), fmaxf(sv[2][i], sv[3][i]));
#pragma unroll
    for (int m = 1; m < 16; m <<= 1)
#pragma unroll
      for (int i = 0; i < 4; i++) rmax[i] = fmaxf(rmax[i], __shfl_xor(rmax[i], m, 64));
    float pw[4][4], rsum[4];
#pragma unroll
    for (int i = 0; i < 4; i++) {
      float mn = fmaxf(mrow[i], rmax[i]);
      float al = __expf(mrow[i] - mn);
      mrow[i] = mn;
      lsum[i] *= al;
#pragma unroll
      for (int cf = 0; cf < 4; cf++) acc_o[cf][i] *= al;
      rsum[i] = 0.f;
    }
#pragma unroll
    for (int cf = 0; cf < 4; cf++)
#pragma unroll
      for (int i = 0; i < 4; i++) {
        float p = __expf(sv[cf][i] - mrow[i]);
        pw[cf][i] = p;
        rsum[i] += p;
      }
#pragma unroll
    for (int m = 1; m < 16; m <<= 1)
#pragma unroll
      for (int i = 0; i < 4; i++) rsum[i] += __shfl_xor(rsum[i], m, 64);
#pragma unroll
    for (int i = 0; i < 4; i++) lsum[i] += rsum[i];

    // zero Pskew (own wave's 16 rows x 128 cols), then scatter P into Pmain+Pskew
    const uint4 z4 = make_uint4(0u, 0u, 0u, 0u);
#pragma unroll
    for (int s = 0; s < 4; s++) {
      int tau = lane + 64 * s;  // 0..255 = 16 rows * 16 chunks
      int rr = w * 16 + (tau >> 4), cc = (tau & 15) * 8;
      *(uint4*)&buf2[rr * 136 + cc] = z4;
    }
    asm volatile("s_waitcnt lgkmcnt(0)" ::: "memory");
#pragma unroll
    for (int cf = 0; cf < 4; cf++)
#pragma unroll
      for (int i = 0; i < 4; i++) {
        int li = w * 16 + hi * 4 + i;
        int ri = cf * 16 + l15;
        f16 ph = (f16)pw[cf][i];
        buf4[li * 72 + ri] = ph;
        buf2[li * 136 + 63 + ri - li] = ph;  // skew: col = 63 + r - l
      }
    __syncthreads();  // B3: QR gather reads done -> buf3 reusable
#pragma unroll
    for (int s = 0; s < 4; s++) {
      int tau = tid + 256 * s;
      int d = tau >> 4, c = (tau & 15) * 8;
      *(uint4*)&buf3[d * 136 + c] = rvreg[s];
    }
    __syncthreads();  // B4

    // O += P @ V  (B-frag rows = d from V^T tile)
#pragma unroll
    for (int ks = 0; ks < 2; ks++) {
      f16x8 pa = *(const f16x8*)&buf4[(w * 16 + l15) * 72 + ks * 32 + hi * 8];
#pragma unroll
      for (int cf = 0; cf < 4; cf++) {
        f16x8 vb = *(const f16x8*)&buf1[(cf * 16 + l15) * 72 + ks * 32 + hi * 8];
        acc_o[cf] = mfma16(pa, vb, acc_o[cf]);
      }
    }
    // O += Pskew @ relV_band  (K-dim = 128)
#pragma unroll
    for (int ks = 0; ks < 4; ks++) {
      f16x8 pa = *(const f16x8*)&buf2[(w * 16 + l15) * 136 + ks * 32 + hi * 8];
#pragma unroll
      for (int cf = 0; cf < 4; cf++) {
        f16x8 rb = *(const f16x8*)&buf3[(cf * 16 + l15) * 136 + ks * 32 + hi * 8];
        acc_o[cf] = mfma16(pa, rb, acc_o[cf]);
      }
    }
  }
  // epilogue: normalize, store fp16 to AO[b*1024+l][h*64+d]
#pragma unroll
  for (int cf = 0; cf < 4; cf++)
#pragma unroll
    for (int i = 0; i < 4; i++) {
      float v = acc_o[cf][i] / lsum[i];
      AO[((long)(b * 1024 + l0 + w * 16 + hi * 4 + i)) * 1024 + h * 64 + cf * 16 + l15] =
          (f16)v;
    }
}

// ---------------- launch ----------------
extern "C" void kernel_launch(void* const* d_in, const int* in_sizes, int n_in,
                              void* d_out, int out_size, void* d_ws, size_t ws_size,
                              hipStream_t stream) {
  const float* x = (const float*)d_in[0];
  const float* Wq = (const float*)d_in[1];
  const float* bq = (const float*)d_in[2];
  const float* Wk = (const float*)d_in[3];
  const float* bk = (const float*)d_in[4];
  const float* Wv = (const float*)d_in[5];
  const float* bv = (const float*)d_in[6];
  const float* Wo = (const float*)d_in[7];
  const float* bo = (const float*)d_in[8];
  const float* relk = (const float*)d_in[9];
  const float* relv = (const float*)d_in[10];
  float* out = (float*)d_out;

  char* ws = (char*)d_ws;
  size_t off = 0;
  auto alloc = [&](size_t bytes) {
    char* p = ws + off;
    off += (bytes + 255) & ~(size_t)255;
    return p;
  };
  f16* xh = (f16*)alloc(8192ull * 1024 * 2);
  f16* Wqh = (f16*)alloc(1024ull * 1024 * 2);
  f16* Wkh = (f16*)alloc(1024ull * 1024 * 2);
  f16* Wvh = (f16*)alloc(1024ull * 1024 * 2);
  f16* Woh = (f16*)alloc(1024ull * 1024 * 2);
  f16* relKh = (f16*)alloc(2048ull * 64 * 2);
  f16* relVTh = (f16*)alloc(64ull * 2048 * 2);
  f16* Qh = (f16*)alloc(8192ull * 1024 * 2);
  f16* Kh = (f16*)alloc(8192ull * 1024 * 2);
  f16* Vth = (f16*)alloc(1024ull * 8192 * 2);
  f16* AOh = (f16*)alloc(8192ull * 1024 * 2);
  if (ws_size < off) return;  // workspace too small: fail loudly at validation

  pack_f16_kernel<<<32768, 256, 0, stream>>>(x, xh, 8192 * 1024);
  pack_f16_kernel<<<4096, 256, 0, stream>>>(Wq, Wqh, 1024 * 1024);
  pack_f16_kernel<<<4096, 256, 0, stream>>>(Wk, Wkh, 1024 * 1024);
  pack_f16_kernel<<<4096, 256, 0, stream>>>(Wv, Wvh, 1024 * 1024);
  pack_f16_kernel<<<4096, 256, 0, stream>>>(Wo, Woh, 1024 * 1024);
  pack_f16_kernel<<<512, 256, 0, stream>>>(relk, relKh, 2047 * 64);
  pack_relvt_kernel<<<512, 256, 0, stream>>>(relv, relVTh);

  dim3 g1(8, 64);  // N/128, M/128
  gemm_bt<0, 0><<<g1, 256, 0, stream>>>(xh, Wqh, bq, Qh, 8192, 1024, 1024, 1.0f);
  gemm_bt<0, 0><<<g1, 256, 0, stream>>>(xh, Wkh, bk, Kh, 8192, 1024, 1024, 0.125f);
  dim3 g2(64, 8);  // V^T = Wv @ x^T : M=1024, N=8192
  gemm_bt<0, 1><<<g2, 256, 0, stream>>>(Wvh, xh, bv, Vth, 1024, 8192, 1024, 1.0f);

  attn_kernel<<<dim3(16, 128), 256, 0, stream>>>(Qh, Kh, Vth, relKh, relVTh, AOh);

  gemm_bt<1, 0><<<g1, 256, 0, stream>>>(AOh, Woh, bo, out, 8192, 1024, 1024, 1.0f);
}